// Round 8
// baseline (330.360 us; speedup 1.0000x reference)
//
#include <hip/hip_runtime.h>
#include <hip/hip_bf16.h>

typedef __attribute__((ext_vector_type(8))) short short8;
typedef __attribute__((ext_vector_type(4))) float f32x4;

__device__ __forceinline__ unsigned int pk_bf16(float a, float b) {
  __hip_bfloat162 h = __float22bfloat162_rn(make_float2(a, b));
  return *(unsigned int*)&h;
}
__device__ __forceinline__ unsigned short s_bf16(float a) {
  __hip_bfloat16 h = __float2bfloat16(a);
  return *(unsigned short*)&h;
}

// cvt two float4 (k0..3, k16..19) -> short8 A-frag
__device__ __forceinline__ short8 cvt_af(const float4& lo, const float4& hi) {
  union { uint4 u; short8 v; } r;
  r.u.x = pk_bf16(lo.x, lo.y);
  r.u.y = pk_bf16(lo.z, lo.w);
  r.u.z = pk_bf16(hi.x, hi.y);
  r.u.w = pk_bf16(hi.z, hi.w);
  return r.v;
}

// combine two 8B chunks -> short8 A-frag (bf16 source)
__device__ __forceinline__ short8 mk_af(uint2 a, uint2 b) {
  union { uint2 u[2]; short8 v; } r;
  r.u[0] = a; r.u[1] = b;
  return r.v;
}

// ---------------------------------------------------------------------------
// prep (fused): build all MFMA B-fragments directly (verified r3-r6).
// ---------------------------------------------------------------------------
__global__ __launch_bounds__(256) void prep_kernel(
    const float* __restrict__ W1, const float* __restrict__ W2,
    const float* __restrict__ W3,
    unsigned short* __restrict__ fL1, unsigned short* __restrict__ fL2,
    unsigned short* __restrict__ fL3) {
  const int w = blockIdx.x * 4 + (threadIdx.x >> 6);
  const int lane = threadIdx.x & 63;
  const int rlo = lane & 15;
  const int q4 = (lane >> 4) << 2;

  if (w < 512) {
    const int nt = w >> 5, kk = w & 31;
    const int col = nt * 16 + rlo;
    const int k0 = kk * 32 + q4;
    float pc[8], ps[8], dc[8], dsn[8], acc[8];
#pragma unroll
    for (int e = 0; e < 8; ++e) {
      int ke = k0 + (e & 3) + ((e >> 2) << 4);
      float ang = (float)ke * 6.135923151542565e-3f;  // 2*pi/1024
      float s, c;
      __sincosf(ang, &s, &c);
      dc[e] = c; dsn[e] = s;
      pc[e] = 1.f; ps[e] = 0.f;
      acc[e] = 0.f;
    }
    const float* pw = W1 + col;
#pragma unroll 2
    for (int m = 0; m < 192; ++m) {
      float wre = pw[0];     // W1[2m][col]
      float wio = pw[256];   // W1[2m+1][col]
      pw += 512;
#pragma unroll
      for (int e = 0; e < 8; ++e) {
        acc[e] = fmaf(pc[e], wre, acc[e]);
        acc[e] = fmaf(-ps[e], wio, acc[e]);
        float c2 = pc[e] * dc[e] - ps[e] * dsn[e];
        float s2 = ps[e] * dc[e] + pc[e] * dsn[e];
        pc[e] = c2; ps[e] = s2;
      }
    }
    uint4 v;
    v.x = pk_bf16(acc[0], acc[1]);
    v.y = pk_bf16(acc[2], acc[3]);
    v.z = pk_bf16(acc[4], acc[5]);
    v.w = pk_bf16(acc[6], acc[7]);
    *(uint4*)(fL1 + ((size_t)w * 64 + lane) * 8) = v;
  } else if (w < 576) {
    const int tl = w - 512;
    const int nt = tl >> 3, kk = tl & 7;
    const int col = nt * 16 + rlo;
    const int k0 = kk * 32 + q4;
    float a[8];
#pragma unroll
    for (int e = 0; e < 8; ++e) {
      int ke = k0 + (e & 3) + ((e >> 2) << 4);
      a[e] = W2[ke * 128 + col];
    }
    uint4 v;
    v.x = pk_bf16(a[0], a[1]); v.y = pk_bf16(a[2], a[3]);
    v.z = pk_bf16(a[4], a[5]); v.w = pk_bf16(a[6], a[7]);
    *(uint4*)(fL2 + ((size_t)tl * 64 + lane) * 8) = v;
  } else {
    const int tl = w - 576;
    const int nt = tl >> 2, kk = tl & 3;
    const int col = nt * 16 + rlo;
    const int k0 = kk * 32 + q4;
    float a[8];
#pragma unroll
    for (int e = 0; e < 8; ++e) {
      int ke = k0 + (e & 3) + ((e >> 2) << 4);
      a[e] = W3[ke * 32 + col];
    }
    uint4 v;
    v.x = pk_bf16(a[0], a[1]); v.y = pk_bf16(a[2], a[3]);
    v.z = pk_bf16(a[4], a[5]); v.w = pk_bf16(a[6], a[7]);
    *(uint4*)(fL3 + ((size_t)tl * 64 + lane) * 8) = v;
  }
}

// ---------------------------------------------------------------------------
// gemm1: h1 = leaky(x @ DW1 + b1), h1 -> global ws (bf16 [32768][256]).
// 1024 blocks x 256 thr (4 waves), BM=32. Wave: rows [row0,row0+32),
// cols [64*wid, 64*wid+64) = 2 m-tiles x 4 c-tiles. No LDS, no barriers.
// 4 blocks/CU x 4 waves = 16 waves/CU; regs sized for 4 waves/SIMD so the
// 1-step prefetch survives in registers -> deep memory pipeline.
// ---------------------------------------------------------------------------
__global__ __launch_bounds__(256, 4) void gemm1_kernel(
    const float* __restrict__ x, const float* __restrict__ b1,
    const unsigned short* __restrict__ fL1,
    unsigned short* __restrict__ h1g) {
  const int t = threadIdx.x;
  const int lane = t & 63;
  const int wid = t >> 6;
  const int rlo = lane & 15;
  const int g4 = (lane >> 4) << 2;
  const size_t row0 = (size_t)blockIdx.x * 32;

  const float* xb = x + (row0 + rlo) * 1024 + g4;
  const unsigned short* fb = fL1 + ((size_t)wid * 4 * 32 * 512) + (size_t)lane * 8;

  f32x4 acc[2][4] = {};
  float4 ac[2][2], an[2][2];
  short8 bc[4], bn[4];

#pragma unroll
  for (int m = 0; m < 2; ++m) {
    ac[m][0] = *(const float4*)(xb + m * 16384);
    ac[m][1] = *(const float4*)(xb + m * 16384 + 16);
  }
#pragma unroll
  for (int c = 0; c < 4; ++c)
    bc[c] = *(const short8*)(fb + (size_t)c * 32 * 512);

#pragma unroll 2
  for (int kk = 0; kk < 32; ++kk) {
    if (kk < 31) {
#pragma unroll
      for (int m = 0; m < 2; ++m) {
        an[m][0] = *(const float4*)(xb + m * 16384 + (kk + 1) * 32);
        an[m][1] = *(const float4*)(xb + m * 16384 + (kk + 1) * 32 + 16);
      }
#pragma unroll
      for (int c = 0; c < 4; ++c)
        bn[c] = *(const short8*)(fb + ((size_t)c * 32 + kk + 1) * 512);
    }
    short8 af[2];
#pragma unroll
    for (int m = 0; m < 2; ++m) af[m] = cvt_af(ac[m][0], ac[m][1]);
#pragma unroll
    for (int m = 0; m < 2; ++m)
#pragma unroll
      for (int c = 0; c < 4; ++c)
        acc[m][c] = __builtin_amdgcn_mfma_f32_16x16x32_bf16(af[m], bc[c], acc[m][c], 0, 0, 0);
    if (kk < 31) {
#pragma unroll
      for (int m = 0; m < 2; ++m) { ac[m][0] = an[m][0]; ac[m][1] = an[m][1]; }
#pragma unroll
      for (int c = 0; c < 4; ++c) bc[c] = bn[c];
    }
  }

  // epilogue: bias + leaky -> h1g (bf16)
  float bv[4];
#pragma unroll
  for (int c = 0; c < 4; ++c) bv[c] = b1[wid * 64 + c * 16 + rlo];
#pragma unroll
  for (int m = 0; m < 2; ++m)
#pragma unroll
    for (int c = 0; c < 4; ++c)
#pragma unroll
      for (int r = 0; r < 4; ++r) {
        float v = acc[m][c][r] + bv[c];
        v = fmaxf(v, 0.01f * v);
        h1g[(row0 + m * 16 + g4 + r) * 256 + wid * 64 + c * 16 + rlo] = s_bf16(v);
      }
}

// ---------------------------------------------------------------------------
// mlp2: h2 = leaky(h1 @ W2 + b2); out = h2 @ W3 + b3.
// 1024 blocks x 256 thr, BM=32. L2: wave wid -> 32 cols of h2 (2 c-tiles),
// A-frags straight from global h1 (bf16, no cvt). h2 via LDS (1 barrier).
// L3: waves 0,1 compute the two 16-row tiles.
// ---------------------------------------------------------------------------
#define H2S 132

__global__ __launch_bounds__(256, 4) void mlp2_kernel(
    const unsigned short* __restrict__ h1g,
    const float* __restrict__ b2, const float* __restrict__ b3,
    const unsigned short* __restrict__ fL2, const unsigned short* __restrict__ fL3,
    float* __restrict__ out) {
  __shared__ unsigned short h2s[32 * H2S];
  const int t = threadIdx.x;
  const int lane = t & 63;
  const int wid = t >> 6;
  const int rlo = lane & 15;
  const int g4 = (lane >> 4) << 2;
  const size_t row0 = (size_t)blockIdx.x * 32;

  const unsigned short* hb = h1g + (row0 + rlo) * 256 + g4;

  f32x4 a2[2][2] = {};
  uint2 acu[2][2], anx[2][2];
  short8 b2c[2], b2n[2];
#pragma unroll
  for (int m = 0; m < 2; ++m) {
    acu[m][0] = *(const uint2*)(hb + m * 4096);
    acu[m][1] = *(const uint2*)(hb + m * 4096 + 16);
  }
#pragma unroll
  for (int c = 0; c < 2; ++c)
    b2c[c] = *(const short8*)(fL2 + (((size_t)(wid * 2 + c) * 8) * 64 + lane) * 8);

#pragma unroll
  for (int ks = 0; ks < 8; ++ks) {
    if (ks < 7) {
#pragma unroll
      for (int m = 0; m < 2; ++m) {
        anx[m][0] = *(const uint2*)(hb + m * 4096 + (ks + 1) * 32);
        anx[m][1] = *(const uint2*)(hb + m * 4096 + (ks + 1) * 32 + 16);
      }
#pragma unroll
      for (int c = 0; c < 2; ++c)
        b2n[c] = *(const short8*)(fL2 + (((size_t)(wid * 2 + c) * 8 + ks + 1) * 64 + lane) * 8);
    }
    short8 af[2];
#pragma unroll
    for (int m = 0; m < 2; ++m) af[m] = mk_af(acu[m][0], acu[m][1]);
#pragma unroll
    for (int m = 0; m < 2; ++m)
#pragma unroll
      for (int c = 0; c < 2; ++c)
        a2[m][c] = __builtin_amdgcn_mfma_f32_16x16x32_bf16(af[m], b2c[c], a2[m][c], 0, 0, 0);
    if (ks < 7) {
#pragma unroll
      for (int m = 0; m < 2; ++m) { acu[m][0] = anx[m][0]; acu[m][1] = anx[m][1]; }
#pragma unroll
      for (int c = 0; c < 2; ++c) b2c[c] = b2n[c];
    }
  }
  {
    float bv[2];
#pragma unroll
    for (int c = 0; c < 2; ++c) bv[c] = b2[wid * 32 + c * 16 + rlo];
#pragma unroll
    for (int m = 0; m < 2; ++m)
#pragma unroll
      for (int c = 0; c < 2; ++c)
#pragma unroll
        for (int r = 0; r < 4; ++r) {
          float v = a2[m][c][r] + bv[c];
          v = fmaxf(v, 0.01f * v);
          h2s[(m * 16 + g4 + r) * H2S + wid * 32 + c * 16 + rlo] = s_bf16(v);
        }
  }
  __syncthreads();

  if (wid < 2) {
    f32x4 a3[2] = {};
#pragma unroll
    for (int ks = 0; ks < 4; ++ks) {
      const unsigned short* p = h2s + (wid * 16 + rlo) * H2S + ks * 32 + g4;
      short8 af = mk_af(*(const uint2*)p, *(const uint2*)(p + 16));
#pragma unroll
      for (int c = 0; c < 2; ++c) {
        short8 bfr = *(const short8*)(fL3 + (((size_t)c * 4 + ks) * 64 + lane) * 8);
        a3[c] = __builtin_amdgcn_mfma_f32_16x16x32_bf16(af, bfr, a3[c], 0, 0, 0);
      }
    }
    float bv[2];
    bv[0] = b3[rlo];
    bv[1] = b3[16 + rlo];
#pragma unroll
    for (int c = 0; c < 2; ++c)
#pragma unroll
      for (int r = 0; r < 4; ++r)
        out[(row0 + wid * 16 + g4 + r) * 32 + c * 16 + rlo] = a3[c][r] + bv[c];
  }
}

// ---------------------------------------------------------------------------
extern "C" void kernel_launch(void* const* d_in, const int* in_sizes, int n_in,
                              void* d_out, int out_size, void* d_ws, size_t ws_size,
                              hipStream_t stream) {
  const float* x  = (const float*)d_in[0];
  const float* W1 = (const float*)d_in[1];
  const float* b1 = (const float*)d_in[2];
  const float* W2 = (const float*)d_in[3];
  const float* b2 = (const float*)d_in[4];
  const float* W3 = (const float*)d_in[5];
  const float* b3 = (const float*)d_in[6];
  float* out = (float*)d_out;

  char* ws = (char*)d_ws;
  unsigned short* fL1 = (unsigned short*)ws;                 // 512 KiB
  unsigned short* fL2 = (unsigned short*)(ws + 524288);      //  64 KiB
  unsigned short* fL3 = (unsigned short*)(ws + 589824);      //   8 KiB
  unsigned short* h1g = (unsigned short*)(ws + 1048576);     //  16 MiB (32768x256 bf16)

  hipLaunchKernelGGL(prep_kernel, dim3(146), dim3(256), 0, stream,
                     W1, W2, W3, fL1, fL2, fL3);
  hipLaunchKernelGGL(gemm1_kernel, dim3(1024), dim3(256), 0, stream,
                     x, b1, fL1, h1g);
  hipLaunchKernelGGL(mlp2_kernel, dim3(1024), dim3(256), 0, stream,
                     h1g, b2, b3, fL2, fL3, out);
}

// Round 10
// 285.950 us; speedup vs baseline: 1.1553x; 1.1553x over previous
//
#include <hip/hip_runtime.h>
#include <hip/hip_bf16.h>

typedef __attribute__((ext_vector_type(8))) short short8;
typedef __attribute__((ext_vector_type(4))) float f32x4;

__device__ __forceinline__ unsigned int pk_bf16(float a, float b) {
  __hip_bfloat162 h = __float22bfloat162_rn(make_float2(a, b));
  return *(unsigned int*)&h;
}
__device__ __forceinline__ unsigned short s_bf16(float a) {
  __hip_bfloat16 h = __float2bfloat16(a);
  return *(unsigned short*)&h;
}

// cvt two float4 (k0..3, k16..19) -> short8 A-frag
__device__ __forceinline__ short8 cvt_af(const float4& lo, const float4& hi) {
  union { uint4 u; short8 v; } r;
  r.u.x = pk_bf16(lo.x, lo.y);
  r.u.y = pk_bf16(lo.z, lo.w);
  r.u.z = pk_bf16(hi.x, hi.y);
  r.u.w = pk_bf16(hi.z, hi.w);
  return r.v;
}

// combine two 8B chunks -> short8 A-frag (bf16 source)
__device__ __forceinline__ short8 mk_af(uint2 a, uint2 b) {
  union { uint2 u[2]; short8 v; } r;
  r.u[0] = a; r.u[1] = b;
  return r.v;
}

// async global->LDS, 16B per lane. LDS dest = wave-uniform base + lane*16;
// global src is per-lane (pre-swizzled source trick, m173).
__device__ __forceinline__ void gl_lds16(const void* g, void* l) {
  __builtin_amdgcn_global_load_lds(
      (const __attribute__((address_space(1))) unsigned int*)g,
      (__attribute__((address_space(3))) unsigned int*)l, 16, 0, 0);
}

// ---------------------------------------------------------------------------
// prep (fused): build all MFMA B-fragments directly (verified r3-r8).
// ---------------------------------------------------------------------------
__global__ __launch_bounds__(256) void prep_kernel(
    const float* __restrict__ W1, const float* __restrict__ W2,
    const float* __restrict__ W3,
    unsigned short* __restrict__ fL1, unsigned short* __restrict__ fL2,
    unsigned short* __restrict__ fL3) {
  const int w = blockIdx.x * 4 + (threadIdx.x >> 6);
  const int lane = threadIdx.x & 63;
  const int rlo = lane & 15;
  const int q4 = (lane >> 4) << 2;

  if (w < 512) {
    const int nt = w >> 5, kk = w & 31;
    const int col = nt * 16 + rlo;
    const int k0 = kk * 32 + q4;
    float pc[8], ps[8], dc[8], dsn[8], acc[8];
#pragma unroll
    for (int e = 0; e < 8; ++e) {
      int ke = k0 + (e & 3) + ((e >> 2) << 4);
      float ang = (float)ke * 6.135923151542565e-3f;  // 2*pi/1024
      float s, c;
      __sincosf(ang, &s, &c);
      dc[e] = c; dsn[e] = s;
      pc[e] = 1.f; ps[e] = 0.f;
      acc[e] = 0.f;
    }
    const float* pw = W1 + col;
#pragma unroll 2
    for (int m = 0; m < 192; ++m) {
      float wre = pw[0];     // W1[2m][col]
      float wio = pw[256];   // W1[2m+1][col]
      pw += 512;
#pragma unroll
      for (int e = 0; e < 8; ++e) {
        acc[e] = fmaf(pc[e], wre, acc[e]);
        acc[e] = fmaf(-ps[e], wio, acc[e]);
        float c2 = pc[e] * dc[e] - ps[e] * dsn[e];
        float s2 = ps[e] * dc[e] + pc[e] * dsn[e];
        pc[e] = c2; ps[e] = s2;
      }
    }
    uint4 v;
    v.x = pk_bf16(acc[0], acc[1]);
    v.y = pk_bf16(acc[2], acc[3]);
    v.z = pk_bf16(acc[4], acc[5]);
    v.w = pk_bf16(acc[6], acc[7]);
    *(uint4*)(fL1 + ((size_t)w * 64 + lane) * 8) = v;
  } else if (w < 576) {
    const int tl = w - 512;
    const int nt = tl >> 3, kk = tl & 7;
    const int col = nt * 16 + rlo;
    const int k0 = kk * 32 + q4;
    float a[8];
#pragma unroll
    for (int e = 0; e < 8; ++e) {
      int ke = k0 + (e & 3) + ((e >> 2) << 4);
      a[e] = W2[ke * 128 + col];
    }
    uint4 v;
    v.x = pk_bf16(a[0], a[1]); v.y = pk_bf16(a[2], a[3]);
    v.z = pk_bf16(a[4], a[5]); v.w = pk_bf16(a[6], a[7]);
    *(uint4*)(fL2 + ((size_t)tl * 64 + lane) * 8) = v;
  } else {
    const int tl = w - 576;
    const int nt = tl >> 2, kk = tl & 3;
    const int col = nt * 16 + rlo;
    const int k0 = kk * 32 + q4;
    float a[8];
#pragma unroll
    for (int e = 0; e < 8; ++e) {
      int ke = k0 + (e & 3) + ((e >> 2) << 4);
      a[e] = W3[ke * 32 + col];
    }
    uint4 v;
    v.x = pk_bf16(a[0], a[1]); v.y = pk_bf16(a[2], a[3]);
    v.z = pk_bf16(a[4], a[5]); v.w = pk_bf16(a[6], a[7]);
    *(uint4*)(fL3 + ((size_t)tl * 64 + lane) * 8) = v;
  }
}

// ---------------------------------------------------------------------------
// gemm1 (m97-style staged): h1 = leaky(x @ DW1 + b1) -> h1g bf16 [32768][256].
// 512 blocks x 256 thr (4 waves). Block: 64 rows x all 256 cols, K=1024 in
// 16 steps of BK=64. Per step: stage A (fp32, 16 KB) + B (frag-order bf16,
// 32 KB) via global_load_lds w16, barrier, ds_read frags + 32 MFMA/wave,
// barrier. A uses granule-XOR swizzle applied on the GLOBAL SOURCE side
// (linear LDS dest) and the same XOR on the read -> conflict-free.
// Single buffer; 2-3 co-resident blocks/CU absorb the vmcnt(0) drain.
// ---------------------------------------------------------------------------
__global__ __launch_bounds__(256, 3) void gemm1_kernel(
    const float* __restrict__ x, const float* __restrict__ b1,
    const unsigned short* __restrict__ fL1,
    unsigned short* __restrict__ h1g) {
  __shared__ float As[4096];            // 64 rows x 64 cols fp32 (16 KB)
  __shared__ unsigned short Bs[16384];  // 32 frag tiles x 1 KB (32 KB)
  const int t = threadIdx.x;
  const int lane = t & 63;
  const int wid = t >> 6;
  const int rlo = lane & 15;
  const int q = lane >> 4;        // 0..3
  const size_t row0 = (size_t)blockIdx.x * 64;

  f32x4 acc[4][4] = {};

  for (int s = 0; s < 16; ++s) {
    // ---- stage A: wave w covers rows [w*16, w*16+16), 4 insts of 4 rows.
    // lane: row-in-4 = q, granule = rlo; fetch global granule rlo^(row&7).
#pragma unroll
    for (int i = 0; i < 4; ++i) {
      int row = wid * 16 + i * 4 + q;
      int gsrc = rlo ^ (row & 7);
      gl_lds16(x + (row0 + row) * 1024 + s * 64 + gsrc * 4,
               &As[(wid * 16 + i * 4) * 64]);
    }
    // ---- stage B: wave w covers n-tiles w*4..w*4+3, kk = 2s, 2s+1.
#pragma unroll
    for (int c = 0; c < 4; ++c)
#pragma unroll
      for (int j = 0; j < 2; ++j) {
        int tl = (wid * 4 + c) * 32 + 2 * s + j;
        gl_lds16(fL1 + (size_t)tl * 512 + lane * 8,
                 &Bs[((wid * 4 + c) * 2 + j) * 512]);
      }
    __syncthreads();   // vmcnt(0) drain: staged tile visible

    // ---- compute: 2 kk-substeps of K=32
#pragma unroll
    for (int j = 0; j < 2; ++j) {
      short8 bf_[4];
#pragma unroll
      for (int c = 0; c < 4; ++c)
        bf_[c] = *(const short8*)(Bs + ((wid * 4 + c) * 2 + j) * 512 + lane * 8);
      short8 af_[4];
#pragma unroll
      for (int m = 0; m < 4; ++m) {
        int row = m * 16 + rlo;
        int gl = (j * 8 + q) ^ (rlo & 7);
        int gh = (j * 8 + q + 4) ^ (rlo & 7);
        float4 lo = *(const float4*)(As + row * 64 + gl * 4);
        float4 hi = *(const float4*)(As + row * 64 + gh * 4);
        af_[m] = cvt_af(lo, hi);
      }
#pragma unroll
      for (int m = 0; m < 4; ++m)
#pragma unroll
        for (int c = 0; c < 4; ++c)
          acc[m][c] = __builtin_amdgcn_mfma_f32_16x16x32_bf16(af_[m], bf_[c], acc[m][c], 0, 0, 0);
    }
    __syncthreads();   // all waves done reading before next overwrite
  }

  // ---- epilogue: bias + leaky -> h1g (bf16). Wave w: cols [w*64, w*64+64).
  float bv[4];
#pragma unroll
  for (int c = 0; c < 4; ++c) bv[c] = b1[wid * 64 + c * 16 + rlo];
  const int g4 = q * 4;
#pragma unroll
  for (int m = 0; m < 4; ++m)
#pragma unroll
    for (int c = 0; c < 4; ++c)
#pragma unroll
      for (int r = 0; r < 4; ++r) {
        float v = acc[m][c][r] + bv[c];
        v = fmaxf(v, 0.01f * v);
        h1g[(row0 + m * 16 + g4 + r) * 256 + wid * 64 + c * 16 + rlo] = s_bf16(v);
      }
}

// ---------------------------------------------------------------------------
// mlp2: h2 = leaky(h1 @ W2 + b2); out = h2 @ W3 + b3.  (unchanged control)
// ---------------------------------------------------------------------------
#define H2S 132

__global__ __launch_bounds__(256, 4) void mlp2_kernel(
    const unsigned short* __restrict__ h1g,
    const float* __restrict__ b2, const float* __restrict__ b3,
    const unsigned short* __restrict__ fL2, const unsigned short* __restrict__ fL3,
    float* __restrict__ out) {
  __shared__ unsigned short h2s[32 * H2S];
  const int t = threadIdx.x;
  const int lane = t & 63;
  const int wid = t >> 6;
  const int rlo = lane & 15;
  const int g4 = (lane >> 4) << 2;
  const size_t row0 = (size_t)blockIdx.x * 32;

  const unsigned short* hb = h1g + (row0 + rlo) * 256 + g4;

  f32x4 a2[2][2] = {};
  uint2 acu[2][2], anx[2][2];
  short8 b2c[2], b2n[2];
#pragma unroll
  for (int m = 0; m < 2; ++m) {
    acu[m][0] = *(const uint2*)(hb + m * 4096);
    acu[m][1] = *(const uint2*)(hb + m * 4096 + 16);
  }
#pragma unroll
  for (int c = 0; c < 2; ++c)
    b2c[c] = *(const short8*)(fL2 + (((size_t)(wid * 2 + c) * 8) * 64 + lane) * 8);

#pragma unroll
  for (int ks = 0; ks < 8; ++ks) {
    if (ks < 7) {
#pragma unroll
      for (int m = 0; m < 2; ++m) {
        anx[m][0] = *(const uint2*)(hb + m * 4096 + (ks + 1) * 32);
        anx[m][1] = *(const uint2*)(hb + m * 4096 + (ks + 1) * 32 + 16);
      }
#pragma unroll
      for (int c = 0; c < 2; ++c)
        b2n[c] = *(const short8*)(fL2 + (((size_t)(wid * 2 + c) * 8 + ks + 1) * 64 + lane) * 8);
    }
    short8 af[2];
#pragma unroll
    for (int m = 0; m < 2; ++m) af[m] = mk_af(acu[m][0], acu[m][1]);
#pragma unroll
    for (int m = 0; m < 2; ++m)
#pragma unroll
      for (int c = 0; c < 2; ++c)
        a2[m][c] = __builtin_amdgcn_mfma_f32_16x16x32_bf16(af[m], b2c[c], a2[m][c], 0, 0, 0);
    if (ks < 7) {
#pragma unroll
      for (int m = 0; m < 2; ++m) { acu[m][0] = anx[m][0]; acu[m][1] = anx[m][1]; }
#pragma unroll
      for (int c = 0; c < 2; ++c) b2c[c] = b2n[c];
    }
  }
  {
    float bv[2];
#pragma unroll
    for (int c = 0; c < 2; ++c) bv[c] = b2[wid * 32 + c * 16 + rlo];
#pragma unroll
    for (int m = 0; m < 2; ++m)
#pragma unroll
      for (int c = 0; c < 2; ++c)
#pragma unroll
        for (int r = 0; r < 4; ++r) {
          float v = a2[m][c][r] + bv[c];
          v = fmaxf(v, 0.01f * v);
          h2s[(m * 16 + g4 + r) * H2S + wid * 32 + c * 16 + rlo] = s_bf16(v);
        }
  }
  __syncthreads();

  if (wid < 2) {
    f32x4 a3[2] = {};
#pragma unroll
    for (int ks = 0; ks < 4; ++ks) {
      const unsigned short* p = h2s + (wid * 16 + rlo) * H2S + ks * 32 + g4;
      short8 af = mk_af(*(const uint2*)p, *(const uint2*)(p + 16));
#pragma unroll
      for (int c = 0; c < 2; ++c) {
        short8 bfr = *(const short8*)(fL3 + (((size_t)c * 4 + ks) * 64 + lane) * 8);
        a3[c] = __builtin_amdgcn_mfma_f32_16x16x32_bf16(af, bfr, a3[c], 0, 0, 0);
      }
    }
    float bv[2];
    bv[0] = b3[rlo];
    bv[1] = b3[16 + rlo];
#pragma unroll
    for (int c = 0; c < 2; ++c)
#pragma unroll
      for (int r = 0; r < 4; ++r)
        out[(row0 + wid * 16 + g4 + r) * 32 + c * 16 + rlo] = a3[c][r] + bv[c];
  }
}

// ---------------------------------------------------------------------------
extern "C" void kernel_launch(void* const* d_in, const int* in_sizes, int n_in,
                              void* d_out, int out_size, void* d_ws, size_t ws_size,
                              hipStream_t stream) {
  const float* x  = (const float*)d_in[0];
  const float* W1 = (const float*)d_in[1];
  const float* b1 = (const float*)d_in[2];
  const float* W2 = (const float*)d_in[3];
  const float* b2 = (const float*)d_in[4];
  const float* W3 = (const float*)d_in[5];
  const float* b3 = (const float*)d_in[6];
  float* out = (float*)d_out;

  char* ws = (char*)d_ws;
  unsigned short* fL1 = (unsigned short*)ws;                 // 512 KiB
  unsigned short* fL2 = (unsigned short*)(ws + 524288);      //  64 KiB
  unsigned short* fL3 = (unsigned short*)(ws + 589824);      //   8 KiB
  unsigned short* h1g = (unsigned short*)(ws + 1048576);     //  16 MiB (32768x256 bf16)

  hipLaunchKernelGGL(prep_kernel, dim3(146), dim3(256), 0, stream,
                     W1, W2, W3, fL1, fL2, fL3);
  hipLaunchKernelGGL(gemm1_kernel, dim3(512), dim3(256), 0, stream,
                     x, b1, fL1, h1g);
  hipLaunchKernelGGL(mlp2_kernel, dim3(1024), dim3(256), 0, stream,
                     h1g, b2, b3, fL2, fL3, out);
}